// Round 1
// baseline (590.910 us; speedup 1.0000x reference)
//
#include <hip/hip_runtime.h>
#include <cstdint>
#include <cstddef>

#define NEG_SLOPE 0.2f
#define EPS_F 1e-16f

static __device__ __forceinline__ float leaky(float x) { return x > 0.f ? x : NEG_SLOPE * x; }

// ---------------- CSR build ----------------

__global__ __launch_bounds__(256) void hist_k(const int* __restrict__ dst, int* __restrict__ cnt, int E) {
    int i = blockIdx.x * blockDim.x + threadIdx.x;
    if (i < E) atomicAdd(&cnt[dst[i]], 1);
}

// single-block exclusive scan over cnt[N] -> off[N+1]
__global__ __launch_bounds__(1024) void scan_k(const int* __restrict__ cnt, int* __restrict__ off, int N) {
    __shared__ int wsum[16];
    int tid = threadIdx.x;
    int lane = tid & 63, wid = tid >> 6;
    int running = 0;
    for (int base = 0; base < N; base += 1024) {
        int i = base + tid;
        int v = (i < N) ? cnt[i] : 0;
        int iv = v;
        #pragma unroll
        for (int d = 1; d < 64; d <<= 1) {
            int t = __shfl_up(iv, d);
            if (lane >= d) iv += t;
        }
        if (lane == 63) wsum[wid] = iv;
        __syncthreads();
        if (tid < 16) {
            int s = wsum[tid];
            #pragma unroll
            for (int d = 1; d < 16; d <<= 1) {
                int t = __shfl_up(s, d);
                if (tid >= d) s += t;
            }
            wsum[tid] = s;
        }
        __syncthreads();
        int add = wid ? wsum[wid - 1] : 0;
        if (i < N) off[i + 1] = running + add + iv;
        int ct = wsum[15];
        __syncthreads();
        running += ct;
    }
    if (tid == 0) off[0] = 0;
}

__global__ __launch_bounds__(256) void scat_k(const int* __restrict__ src, const int* __restrict__ dst,
                                              const int* __restrict__ off, int* __restrict__ cnt,
                                              int* __restrict__ esrc, int E) {
    int i = blockIdx.x * blockDim.x + threadIdx.x;
    if (i < E) {
        int d = dst[i];
        int p = off[d] + atomicAdd(&cnt[d], 1);
        esrc[p] = src[i];
    }
}

// ---------------- GEMM: [N,128] @ [128,M] -> [N,M] ----------------

template <int M>
__global__ __launch_bounds__(M) void gemm_k(const float* __restrict__ X, const float* __restrict__ W,
                                            float* __restrict__ O, int N) {
    constexpr int K = 128, R = 16;
    __shared__ float xs[R * K];
    int row0 = blockIdx.x * R;
    int col = threadIdx.x;
    for (int idx = threadIdx.x; idx < R * K; idx += M) {
        int r = idx >> 7, k = idx & 127;
        int row = row0 + r;
        xs[idx] = (row < N) ? X[(size_t)row * K + k] : 0.f;
    }
    __syncthreads();
    float acc[R];
    #pragma unroll
    for (int r = 0; r < R; ++r) acc[r] = 0.f;
    #pragma unroll 4
    for (int k = 0; k < K; ++k) {
        float w = W[k * M + col];
        #pragma unroll
        for (int r = 0; r < R; ++r) acc[r] = fmaf(xs[r * K + k], w, acc[r]);
    }
    #pragma unroll
    for (int r = 0; r < R; ++r) {
        int row = row0 + r;
        if (row < N) O[(size_t)row * M + col] = acc[r];
    }
}

// ---------------- per-node/head attention logits ----------------

template <int H, int C>
__global__ __launch_bounds__(256) void alpha_k(const float* __restrict__ Hm, const float* __restrict__ a_s,
                                               const float* __restrict__ a_d,
                                               float* __restrict__ aS, float* __restrict__ aD, int N) {
    int t = blockIdx.x * blockDim.x + threadIdx.x;
    int n = t / H, hd = t - n * H;
    if (n >= N) return;
    const float4* hp = reinterpret_cast<const float4*>(Hm + (size_t)n * (H * C) + hd * C);
    const float4* as4 = reinterpret_cast<const float4*>(a_s + hd * C);
    const float4* ad4 = reinterpret_cast<const float4*>(a_d + hd * C);
    float ss = 0.f, sd = 0.f;
    #pragma unroll
    for (int c = 0; c < C / 4; ++c) {
        float4 v = hp[c];
        float4 s4 = as4[c];
        float4 d4 = ad4[c];
        ss += v.x * s4.x + v.y * s4.y + v.z * s4.z + v.w * s4.w;
        sd += v.x * d4.x + v.y * d4.y + v.z * d4.z + v.w * d4.w;
    }
    aS[(size_t)n * H + hd] = ss;
    aD[(size_t)n * H + hd] = sd;
}

// ---------------- segment-softmax aggregation, one wave per dst node ----------------

template <int H, int C>
__global__ __launch_bounds__(256) void agg_k(const float* __restrict__ h, const float* __restrict__ aS,
                                             const float* __restrict__ aD, const int* __restrict__ off,
                                             const int* __restrict__ esrc, const float* __restrict__ bias,
                                             float* __restrict__ out, int N) {
    constexpr int M = H * C;
    constexpr int CPL = M / 64;  // channels per lane (2 for M=128, 1 for M=64)
    int node = (blockIdx.x * blockDim.x + threadIdx.x) >> 6;
    if (node >= N) return;
    int lane = threadIdx.x & 63;

    float adv[H], asv[H];
    #pragma unroll
    for (int q = 0; q < H; ++q) {
        adv[q] = aD[(size_t)node * H + q];
        asv[q] = aS[(size_t)node * H + q];
    }
    // self-loop logit initializes the running max
    float eself[H], m[H];
    #pragma unroll
    for (int q = 0; q < H; ++q) {
        float e = leaky(asv[q] + adv[q]);
        eself[q] = e;
        m[q] = e;
    }
    int s0 = off[node], s1 = off[node + 1];

    // pass 1: segment max (lanes stride over edges)
    for (int i = s0 + lane; i < s1; i += 64) {
        int s = esrc[i];
        #pragma unroll
        for (int q = 0; q < H; ++q) {
            float e = leaky(aS[(size_t)s * H + q] + adv[q]);
            m[q] = fmaxf(m[q], e);
        }
    }
    #pragma unroll
    for (int q = 0; q < H; ++q) {
        #pragma unroll
        for (int d = 1; d < 64; d <<= 1) m[q] = fmaxf(m[q], __shfl_xor(m[q], d));
    }

    // pass 2: exp-sum
    float dsum[H];
    #pragma unroll
    for (int q = 0; q < H; ++q) dsum[q] = 0.f;
    for (int i = s0 + lane; i < s1; i += 64) {
        int s = esrc[i];
        #pragma unroll
        for (int q = 0; q < H; ++q) {
            float e = leaky(aS[(size_t)s * H + q] + adv[q]);
            dsum[q] += __expf(e - m[q]);
        }
    }
    #pragma unroll
    for (int q = 0; q < H; ++q) {
        #pragma unroll
        for (int d = 1; d < 64; d <<= 1) dsum[q] += __shfl_xor(dsum[q], d);
    }
    float selfw[H];
    #pragma unroll
    for (int q = 0; q < H; ++q) {
        selfw[q] = __expf(eself[q] - m[q]);
        dsum[q] += selfw[q];
    }

    // pass 3: unnormalized payload accumulate (whole wave per edge, lane = channel)
    float acc[CPL];
    #pragma unroll
    for (int c = 0; c < CPL; ++c) acc[c] = 0.f;
    const int ch0 = lane * CPL;
    const int hd = ch0 / C;
    for (int i = s0; i < s1; ++i) {
        int s = esrc[i];
        float e = leaky(aS[(size_t)s * H + hd] + adv[hd]);
        float wgt = __expf(e - m[hd]);
        const float* hrow = h + (size_t)s * M;
        if constexpr (CPL == 2) {
            float2 hv = *reinterpret_cast<const float2*>(hrow + ch0);
            acc[0] = fmaf(wgt, hv.x, acc[0]);
            acc[1] = fmaf(wgt, hv.y, acc[1]);
        } else {
            acc[0] = fmaf(wgt, hrow[ch0], acc[0]);
        }
    }
    {  // self loop
        const float* hrow = h + (size_t)node * M;
        float wgt = selfw[hd];
        if constexpr (CPL == 2) {
            float2 hv = *reinterpret_cast<const float2*>(hrow + ch0);
            acc[0] = fmaf(wgt, hv.x, acc[0]);
            acc[1] = fmaf(wgt, hv.y, acc[1]);
        } else {
            acc[0] = fmaf(wgt, hrow[ch0], acc[0]);
        }
    }
    float inv = 1.f / (dsum[hd] + EPS_F);
    if constexpr (CPL == 2) {
        float2 o;
        o.x = acc[0] * inv + bias[ch0];
        o.y = acc[1] * inv + bias[ch0 + 1];
        *reinterpret_cast<float2*>(out + (size_t)node * M + ch0) = o;
    } else {
        out[(size_t)node * M + ch0] = acc[0] * inv + bias[ch0];
    }
}

// ---------------- launch ----------------

extern "C" void kernel_launch(void* const* d_in, const int* in_sizes, int n_in,
                              void* d_out, int out_size, void* d_ws, size_t ws_size,
                              hipStream_t stream) {
    const float* x   = (const float*)d_in[0];
    const int*   ei  = (const int*)d_in[1];
    const float* W0  = (const float*)d_in[2];
    const float* as0 = (const float*)d_in[3];
    const float* ad0 = (const float*)d_in[4];
    const float* b0  = (const float*)d_in[5];
    const float* W1  = (const float*)d_in[6];
    const float* as1 = (const float*)d_in[7];
    const float* ad1 = (const float*)d_in[8];
    const float* b1  = (const float*)d_in[9];
    const float* W2  = (const float*)d_in[10];
    const float* as2 = (const float*)d_in[11];
    const float* ad2 = (const float*)d_in[12];
    const float* b2  = (const float*)d_in[13];

    const int N = in_sizes[0] / 128;  // 50000
    const int E = in_sizes[1] / 2;    // 800000
    const int* esrc_in = ei;
    const int* edst_in = ei + E;

    char* w = (char*)d_ws;
    auto carve = [&](size_t bytes) -> char* {
        char* p = w;
        w += (bytes + 255) & ~(size_t)255;
        return p;
    };
    int*   off  = (int*)carve((size_t)(N + 1) * 4);
    int*   cnt  = (int*)carve((size_t)N * 4);
    int*   es   = (int*)carve((size_t)E * 4);
    float* aS   = (float*)carve((size_t)N * 4 * sizeof(float));
    float* aD   = (float*)carve((size_t)N * 4 * sizeof(float));
    float* bufH = (float*)carve((size_t)N * 128 * sizeof(float));
    float* bufO = (float*)carve((size_t)N * 128 * sizeof(float));
    (void)ws_size; (void)n_in; (void)out_size;

    // CSR by dst (self-loops handled implicitly in agg_k)
    hipMemsetAsync(cnt, 0, (size_t)N * 4, stream);
    hist_k<<<(E + 255) / 256, 256, 0, stream>>>(edst_in, cnt, E);
    scan_k<<<1, 1024, 0, stream>>>(cnt, off, N);
    hipMemsetAsync(cnt, 0, (size_t)N * 4, stream);
    scat_k<<<(E + 255) / 256, 256, 0, stream>>>(esrc_in, edst_in, off, cnt, es, E);

    const int GEMM_GRID = (N + 15) / 16;
    const int AGG_GRID = (N + 3) / 4;

    // layer 0: 128 -> 4x32
    gemm_k<128><<<GEMM_GRID, 128, 0, stream>>>(x, W0, bufH, N);
    alpha_k<4, 32><<<((N * 4) + 255) / 256, 256, 0, stream>>>(bufH, as0, ad0, aS, aD, N);
    agg_k<4, 32><<<AGG_GRID, 256, 0, stream>>>(bufH, aS, aD, off, es, b0, bufO, N);

    // layer 1: 128 -> 4x32
    gemm_k<128><<<GEMM_GRID, 128, 0, stream>>>(bufO, W1, bufH, N);
    alpha_k<4, 32><<<((N * 4) + 255) / 256, 256, 0, stream>>>(bufH, as1, ad1, aS, aD, N);
    agg_k<4, 32><<<AGG_GRID, 256, 0, stream>>>(bufH, aS, aD, off, es, b1, bufO, N);

    // layer 2: 128 -> 1x64
    gemm_k<64><<<GEMM_GRID, 64, 0, stream>>>(bufO, W2, bufH, N);
    alpha_k<1, 64><<<(N + 255) / 256, 256, 0, stream>>>(bufH, as2, ad2, aS, aD, N);
    agg_k<1, 64><<<AGG_GRID, 256, 0, stream>>>(bufH, aS, aD, off, es, b2, (float*)d_out, N);
}

// Round 2
// 448.640 us; speedup vs baseline: 1.3171x; 1.3171x over previous
//
#include <hip/hip_runtime.h>
#include <cstdint>
#include <cstddef>

#define NEG_SLOPE 0.2f
#define EPS_F 1e-16f

static __device__ __forceinline__ float leaky(float x) { return x > 0.f ? x : NEG_SLOPE * x; }

// ---------------- CSR build ----------------

__global__ __launch_bounds__(256) void hist_k(const int* __restrict__ dst, int* __restrict__ cnt, int E) {
    int i = blockIdx.x * blockDim.x + threadIdx.x;
    if (i < E) atomicAdd(&cnt[dst[i]], 1);
}

// single-block exclusive scan over cnt[N] -> off[N+1]
__global__ __launch_bounds__(1024) void scan_k(const int* __restrict__ cnt, int* __restrict__ off, int N) {
    __shared__ int wsum[16];
    int tid = threadIdx.x;
    int lane = tid & 63, wid = tid >> 6;
    int running = 0;
    for (int base = 0; base < N; base += 1024) {
        int i = base + tid;
        int v = (i < N) ? cnt[i] : 0;
        int iv = v;
        #pragma unroll
        for (int d = 1; d < 64; d <<= 1) {
            int t = __shfl_up(iv, d);
            if (lane >= d) iv += t;
        }
        if (lane == 63) wsum[wid] = iv;
        __syncthreads();
        if (tid < 16) {
            int s = wsum[tid];
            #pragma unroll
            for (int d = 1; d < 16; d <<= 1) {
                int t = __shfl_up(s, d);
                if (tid >= d) s += t;
            }
            wsum[tid] = s;
        }
        __syncthreads();
        int add = wid ? wsum[wid - 1] : 0;
        if (i < N) off[i + 1] = running + add + iv;
        int ct = wsum[15];
        __syncthreads();
        running += ct;
    }
    if (tid == 0) off[0] = 0;
}

__global__ __launch_bounds__(256) void scat_k(const int* __restrict__ src, const int* __restrict__ dst,
                                              const int* __restrict__ off, int* __restrict__ cnt,
                                              int* __restrict__ esrc, int E) {
    int i = blockIdx.x * blockDim.x + threadIdx.x;
    if (i < E) {
        int d = dst[i];
        int p = off[d] + atomicAdd(&cnt[d], 1);
        esrc[p] = src[i];
    }
}

// ---------------- GEMM: [N,128] @ [128,M] -> [N,M], register-blocked ----------------
// block = 256 threads, tile = 64 rows x M cols, K-tiles of 32.
// CT = M/4 col-threads (4 cols each), RT = 256/CT row-threads, RPT = 64/RT rows each.

template <int M>
__global__ __launch_bounds__(256) void gemm_k(const float* __restrict__ X, const float* __restrict__ W,
                                              float* __restrict__ O, int N) {
    constexpr int K = 128, BK = 32, ROWS = 64;
    constexpr int CT = M / 4;
    constexpr int RT = 256 / CT;
    constexpr int RPT = ROWS / RT;
    constexpr int XLDA = 68;  // padded, multiple of 4 for b128 alignment
    __shared__ float xsT[BK * XLDA];  // [k][row]
    __shared__ float wt[BK * M];      // [k][col]

    const int tid = threadIdx.x;
    const int cc = tid % CT;
    const int rr = tid / CT;
    const int row0 = blockIdx.x * ROWS;

    float acc[RPT][4];
    #pragma unroll
    for (int r = 0; r < RPT; ++r)
        #pragma unroll
        for (int j = 0; j < 4; ++j) acc[r][j] = 0.f;

    for (int k0 = 0; k0 < K; k0 += BK) {
        // stage X (transposed): 64 rows x 32 k
        #pragma unroll
        for (int t = tid; t < ROWS * (BK / 4); t += 256) {
            int r = t / (BK / 4);
            int kk = t % (BK / 4);
            int row = row0 + r;
            float4 v = make_float4(0.f, 0.f, 0.f, 0.f);
            if (row < N) v = *reinterpret_cast<const float4*>(&X[(size_t)row * K + k0 + kk * 4]);
            xsT[(kk * 4 + 0) * XLDA + r] = v.x;
            xsT[(kk * 4 + 1) * XLDA + r] = v.y;
            xsT[(kk * 4 + 2) * XLDA + r] = v.z;
            xsT[(kk * 4 + 3) * XLDA + r] = v.w;
        }
        // stage W tile: 32 k x M cols
        #pragma unroll
        for (int t = tid; t < BK * CT; t += 256) {
            int k = t / CT, c4 = t % CT;
            *reinterpret_cast<float4*>(&wt[k * M + c4 * 4]) =
                *reinterpret_cast<const float4*>(&W[(size_t)(k0 + k) * M + c4 * 4]);
        }
        __syncthreads();
        #pragma unroll 8
        for (int k = 0; k < BK; ++k) {
            float4 wv = *reinterpret_cast<const float4*>(&wt[k * M + cc * 4]);
            float xr[RPT];
            #pragma unroll
            for (int r4 = 0; r4 < RPT; r4 += 4) {
                float4 xv = *reinterpret_cast<const float4*>(&xsT[k * XLDA + rr * RPT + r4]);
                xr[r4 + 0] = xv.x; xr[r4 + 1] = xv.y; xr[r4 + 2] = xv.z; xr[r4 + 3] = xv.w;
            }
            #pragma unroll
            for (int r = 0; r < RPT; ++r) {
                acc[r][0] = fmaf(xr[r], wv.x, acc[r][0]);
                acc[r][1] = fmaf(xr[r], wv.y, acc[r][1]);
                acc[r][2] = fmaf(xr[r], wv.z, acc[r][2]);
                acc[r][3] = fmaf(xr[r], wv.w, acc[r][3]);
            }
        }
        __syncthreads();
    }
    #pragma unroll
    for (int r = 0; r < RPT; ++r) {
        int row = row0 + rr * RPT + r;
        if (row < N)
            *reinterpret_cast<float4*>(&O[(size_t)row * M + cc * 4]) =
                make_float4(acc[r][0], acc[r][1], acc[r][2], acc[r][3]);
    }
}

// ---------------- per-node/head attention logits ----------------

template <int H, int C>
__global__ __launch_bounds__(256) void alpha_k(const float* __restrict__ Hm, const float* __restrict__ a_s,
                                               const float* __restrict__ a_d,
                                               float* __restrict__ aS, float* __restrict__ aD, int N) {
    int t = blockIdx.x * blockDim.x + threadIdx.x;
    int n = t / H, hd = t - n * H;
    if (n >= N) return;
    const float4* hp = reinterpret_cast<const float4*>(Hm + (size_t)n * (H * C) + hd * C);
    const float4* as4 = reinterpret_cast<const float4*>(a_s + hd * C);
    const float4* ad4 = reinterpret_cast<const float4*>(a_d + hd * C);
    float ss = 0.f, sd = 0.f;
    #pragma unroll
    for (int c = 0; c < C / 4; ++c) {
        float4 v = hp[c];
        float4 s4 = as4[c];
        float4 d4 = ad4[c];
        ss += v.x * s4.x + v.y * s4.y + v.z * s4.z + v.w * s4.w;
        sd += v.x * d4.x + v.y * d4.y + v.z * d4.z + v.w * d4.w;
    }
    aS[(size_t)n * H + hd] = ss;
    aD[(size_t)n * H + hd] = sd;
}

// ---------------- segment-softmax aggregation, one wave per dst node ----------------
// fused online (max, expsum) pass + 8-way batched payload pass

template <int H, int C>
__global__ __launch_bounds__(256) void agg_k(const float* __restrict__ h, const float* __restrict__ aS,
                                             const float* __restrict__ aD, const int* __restrict__ off,
                                             const int* __restrict__ esrc, const float* __restrict__ bias,
                                             float* __restrict__ out, int N) {
    constexpr int M = H * C;
    constexpr int CPL = M / 64;  // 2 for M=128, 1 for M=64
    int node = (blockIdx.x * blockDim.x + threadIdx.x) >> 6;
    if (node >= N) return;
    int lane = threadIdx.x & 63;

    float adv[H], asv[H];
    if constexpr (H == 4) {
        float4 t = *reinterpret_cast<const float4*>(aD + (size_t)node * 4);
        adv[0] = t.x; adv[1] = t.y; adv[2] = t.z; adv[3] = t.w;
        float4 u = *reinterpret_cast<const float4*>(aS + (size_t)node * 4);
        asv[0] = u.x; asv[1] = u.y; asv[2] = u.z; asv[3] = u.w;
    } else {
        adv[0] = aD[node]; asv[0] = aS[node];
    }
    float eself[H], m[H], dsum[H];
    #pragma unroll
    for (int q = 0; q < H; ++q) {
        eself[q] = leaky(asv[q] + adv[q]);
        m[q] = eself[q];
        dsum[q] = 0.f;
    }

    const int s0 = off[node], s1 = off[node + 1];

    // fused pass 1+2: online (max, expsum), lanes stride over edges
    for (int i = s0 + lane; i < s1; i += 64) {
        int s = esrc[i];
        if constexpr (H == 4) {
            float4 u = *reinterpret_cast<const float4*>(aS + (size_t)s * 4);
            float ev[4] = {u.x, u.y, u.z, u.w};
            #pragma unroll
            for (int q = 0; q < 4; ++q) {
                float e = leaky(ev[q] + adv[q]);
                float nm = fmaxf(m[q], e);
                dsum[q] = dsum[q] * __expf(m[q] - nm) + __expf(e - nm);
                m[q] = nm;
            }
        } else {
            float e = leaky(aS[s] + adv[0]);
            float nm = fmaxf(m[0], e);
            dsum[0] = dsum[0] * __expf(m[0] - nm) + __expf(e - nm);
            m[0] = nm;
        }
    }
    // combine (m, dsum) across lanes
    #pragma unroll
    for (int q = 0; q < H; ++q) {
        #pragma unroll
        for (int d = 1; d < 64; d <<= 1) {
            float om = __shfl_xor(m[q], d);
            float od = __shfl_xor(dsum[q], d);
            float nm = fmaxf(m[q], om);
            dsum[q] = dsum[q] * __expf(m[q] - nm) + od * __expf(om - nm);
            m[q] = nm;
        }
        dsum[q] += __expf(eself[q] - m[q]);  // self-loop term
    }

    // pass 3: unnormalized payload accumulate, lane = channel pair, 8-way batched
    const int ch0 = lane * CPL;
    const int hd = ch0 / C;
    const float advh = adv[hd];
    const float Mh = m[hd];
    float acc0 = 0.f, acc1 = 0.f;

    constexpr int B = 8;
    int i = s0;
    for (; i + B <= s1; i += B) {
        int sv[B];
        #pragma unroll
        for (int j = 0; j < B; ++j) sv[j] = esrc[i + j];
        float lv[B];
        #pragma unroll
        for (int j = 0; j < B; ++j) lv[j] = aS[(size_t)sv[j] * H + hd];
        if constexpr (CPL == 2) {
            float2 hv[B];
            #pragma unroll
            for (int j = 0; j < B; ++j)
                hv[j] = *reinterpret_cast<const float2*>(h + (size_t)sv[j] * M + ch0);
            #pragma unroll
            for (int j = 0; j < B; ++j) {
                float wq = __expf(leaky(lv[j] + advh) - Mh);
                acc0 = fmaf(wq, hv[j].x, acc0);
                acc1 = fmaf(wq, hv[j].y, acc1);
            }
        } else {
            float hv[B];
            #pragma unroll
            for (int j = 0; j < B; ++j) hv[j] = h[(size_t)sv[j] * M + ch0];
            #pragma unroll
            for (int j = 0; j < B; ++j) {
                float wq = __expf(leaky(lv[j] + advh) - Mh);
                acc0 = fmaf(wq, hv[j], acc0);
            }
        }
    }
    for (; i < s1; ++i) {
        int s = esrc[i];
        float wq = __expf(leaky(aS[(size_t)s * H + hd] + advh) - Mh);
        if constexpr (CPL == 2) {
            float2 hv = *reinterpret_cast<const float2*>(h + (size_t)s * M + ch0);
            acc0 = fmaf(wq, hv.x, acc0);
            acc1 = fmaf(wq, hv.y, acc1);
        } else {
            acc0 = fmaf(wq, h[(size_t)s * M + ch0], acc0);
        }
    }
    // self loop
    {
        float ws = __expf(eself[hd] - Mh);
        if constexpr (CPL == 2) {
            float2 hv = *reinterpret_cast<const float2*>(h + (size_t)node * M + ch0);
            acc0 = fmaf(ws, hv.x, acc0);
            acc1 = fmaf(ws, hv.y, acc1);
        } else {
            acc0 = fmaf(ws, h[(size_t)node * M + ch0], acc0);
        }
    }
    float inv = 1.f / (dsum[hd] + EPS_F);
    if constexpr (CPL == 2) {
        float2 o;
        o.x = acc0 * inv + bias[ch0];
        o.y = acc1 * inv + bias[ch0 + 1];
        *reinterpret_cast<float2*>(out + (size_t)node * M + ch0) = o;
    } else {
        out[(size_t)node * M + ch0] = acc0 * inv + bias[ch0];
    }
}

// ---------------- launch ----------------

extern "C" void kernel_launch(void* const* d_in, const int* in_sizes, int n_in,
                              void* d_out, int out_size, void* d_ws, size_t ws_size,
                              hipStream_t stream) {
    const float* x   = (const float*)d_in[0];
    const int*   ei  = (const int*)d_in[1];
    const float* W0  = (const float*)d_in[2];
    const float* as0 = (const float*)d_in[3];
    const float* ad0 = (const float*)d_in[4];
    const float* b0  = (const float*)d_in[5];
    const float* W1  = (const float*)d_in[6];
    const float* as1 = (const float*)d_in[7];
    const float* ad1 = (const float*)d_in[8];
    const float* b1  = (const float*)d_in[9];
    const float* W2  = (const float*)d_in[10];
    const float* as2 = (const float*)d_in[11];
    const float* ad2 = (const float*)d_in[12];
    const float* b2  = (const float*)d_in[13];

    const int N = in_sizes[0] / 128;  // 50000
    const int E = in_sizes[1] / 2;    // 800000
    const int* esrc_in = ei;
    const int* edst_in = ei + E;

    char* w = (char*)d_ws;
    auto carve = [&](size_t bytes) -> char* {
        char* p = w;
        w += (bytes + 255) & ~(size_t)255;
        return p;
    };
    int*   off  = (int*)carve((size_t)(N + 1) * 4);
    int*   cnt  = (int*)carve((size_t)N * 4);
    int*   es   = (int*)carve((size_t)E * 4);
    float* aS   = (float*)carve((size_t)N * 4 * sizeof(float));
    float* aD   = (float*)carve((size_t)N * 4 * sizeof(float));
    float* bufH = (float*)carve((size_t)N * 128 * sizeof(float));
    float* bufO = (float*)carve((size_t)N * 128 * sizeof(float));
    (void)ws_size; (void)n_in; (void)out_size;

    // CSR by dst (self-loops handled implicitly in agg_k)
    hipMemsetAsync(cnt, 0, (size_t)N * 4, stream);
    hist_k<<<(E + 255) / 256, 256, 0, stream>>>(edst_in, cnt, E);
    scan_k<<<1, 1024, 0, stream>>>(cnt, off, N);
    hipMemsetAsync(cnt, 0, (size_t)N * 4, stream);
    scat_k<<<(E + 255) / 256, 256, 0, stream>>>(esrc_in, edst_in, off, cnt, es, E);

    const int GEMM_GRID = (N + 63) / 64;
    const int AGG_GRID = (N + 3) / 4;

    // layer 0: 128 -> 4x32
    gemm_k<128><<<GEMM_GRID, 256, 0, stream>>>(x, W0, bufH, N);
    alpha_k<4, 32><<<((N * 4) + 255) / 256, 256, 0, stream>>>(bufH, as0, ad0, aS, aD, N);
    agg_k<4, 32><<<AGG_GRID, 256, 0, stream>>>(bufH, aS, aD, off, es, b0, bufO, N);

    // layer 1: 128 -> 4x32
    gemm_k<128><<<GEMM_GRID, 256, 0, stream>>>(bufO, W1, bufH, N);
    alpha_k<4, 32><<<((N * 4) + 255) / 256, 256, 0, stream>>>(bufH, as1, ad1, aS, aD, N);
    agg_k<4, 32><<<AGG_GRID, 256, 0, stream>>>(bufH, aS, aD, off, es, b1, bufO, N);

    // layer 2: 128 -> 1x64
    gemm_k<64><<<GEMM_GRID, 256, 0, stream>>>(bufO, W2, bufH, N);
    alpha_k<1, 64><<<(N + 255) / 256, 256, 0, stream>>>(bufH, as2, ad2, aS, aD, N);
    agg_k<1, 64><<<AGG_GRID, 256, 0, stream>>>(bufH, aS, aD, off, es, b2, (float*)d_out, N);
}

// Round 3
// 426.488 us; speedup vs baseline: 1.3855x; 1.0519x over previous
//
#include <hip/hip_runtime.h>
#include <cstdint>
#include <cstddef>

#define NEG_SLOPE 0.2f
#define EPS_F 1e-16f
#define NEG_BIG -3.0e38f

static __device__ __forceinline__ float leaky(float x) { return x > 0.f ? x : NEG_SLOPE * x; }

// ---------------- CSR build ----------------

__global__ __launch_bounds__(256) void hist_k(const int* __restrict__ dst, int* __restrict__ cnt, int E) {
    int i = blockIdx.x * blockDim.x + threadIdx.x;
    if (i < E) atomicAdd(&cnt[dst[i]], 1);
}

__global__ __launch_bounds__(1024) void scan_k(const int* __restrict__ cnt, int* __restrict__ off, int N) {
    __shared__ int wsum[16];
    int tid = threadIdx.x;
    int lane = tid & 63, wid = tid >> 6;
    int running = 0;
    for (int base = 0; base < N; base += 1024) {
        int i = base + tid;
        int v = (i < N) ? cnt[i] : 0;
        int iv = v;
        #pragma unroll
        for (int d = 1; d < 64; d <<= 1) {
            int t = __shfl_up(iv, d);
            if (lane >= d) iv += t;
        }
        if (lane == 63) wsum[wid] = iv;
        __syncthreads();
        if (tid < 16) {
            int s = wsum[tid];
            #pragma unroll
            for (int d = 1; d < 16; d <<= 1) {
                int t = __shfl_up(s, d);
                if (tid >= d) s += t;
            }
            wsum[tid] = s;
        }
        __syncthreads();
        int add = wid ? wsum[wid - 1] : 0;
        if (i < N) off[i + 1] = running + add + iv;
        int ct = wsum[15];
        __syncthreads();
        running += ct;
    }
    if (tid == 0) off[0] = 0;
}

__global__ __launch_bounds__(256) void scat_k(const int* __restrict__ src, const int* __restrict__ dst,
                                              const int* __restrict__ off, int* __restrict__ cnt,
                                              int* __restrict__ esrc, int E) {
    int i = blockIdx.x * blockDim.x + threadIdx.x;
    if (i < E) {
        int d = dst[i];
        int p = off[d] + atomicAdd(&cnt[d], 1);
        esrc[p] = src[i];
    }
}

// ---------------- GEMM: [N,128] @ [128,M] -> [N,M], 8x8 (or 4x8) microtile ----------------

template <int M>
__global__ __launch_bounds__(256, 2) void gemm_k(const float* __restrict__ X, const float* __restrict__ W,
                                                 float* __restrict__ O, int N) {
    constexpr int K = 128, BK = 16, ROWS = 128;
    constexpr int CPT = 8;          // cols per thread
    constexpr int CT = M / CPT;     // 16 (M=128) or 8 (M=64)
    constexpr int RT = 256 / CT;    // 16 or 32
    constexpr int RPT = ROWS / RT;  // 8 or 4
    constexpr int XP = ROWS + 4;    // padded leading dim for transposed X
    __shared__ float xsT[BK * XP];  // [k][row]
    __shared__ float wt[BK * M];    // [k][col]

    const int tid = threadIdx.x;
    const int cc = tid % CT;
    const int rr = tid / CT;
    const int row0 = blockIdx.x * ROWS;

    float acc[RPT][CPT];
    #pragma unroll
    for (int r = 0; r < RPT; ++r)
        #pragma unroll
        for (int j = 0; j < CPT; ++j) acc[r][j] = 0.f;

    for (int k0 = 0; k0 < K; k0 += BK) {
        // stage X transposed: ROWS x BK, items = ROWS*(BK/4) float4
        #pragma unroll
        for (int t = tid; t < ROWS * (BK / 4); t += 256) {
            int r = t >> 2;       // row within tile
            int kk = t & 3;       // float4 index within BK
            int row = row0 + r;
            float4 v = make_float4(0.f, 0.f, 0.f, 0.f);
            if (row < N) v = *reinterpret_cast<const float4*>(&X[(size_t)row * K + k0 + kk * 4]);
            xsT[(kk * 4 + 0) * XP + r] = v.x;
            xsT[(kk * 4 + 1) * XP + r] = v.y;
            xsT[(kk * 4 + 2) * XP + r] = v.z;
            xsT[(kk * 4 + 3) * XP + r] = v.w;
        }
        // stage W: BK x M
        #pragma unroll
        for (int t = tid; t < BK * (M / 4); t += 256) {
            int c4 = t % (M / 4);
            int k = t / (M / 4);
            *reinterpret_cast<float4*>(&wt[k * M + c4 * 4]) =
                *reinterpret_cast<const float4*>(&W[(size_t)(k0 + k) * M + c4 * 4]);
        }
        __syncthreads();
        #pragma unroll
        for (int k = 0; k < BK; ++k) {
            float xr[RPT];
            #pragma unroll
            for (int r4 = 0; r4 < RPT; r4 += 4) {
                float4 xv = *reinterpret_cast<const float4*>(&xsT[k * XP + rr * RPT + r4]);
                xr[r4 + 0] = xv.x; xr[r4 + 1] = xv.y; xr[r4 + 2] = xv.z; xr[r4 + 3] = xv.w;
            }
            float wv[CPT];
            #pragma unroll
            for (int c4 = 0; c4 < CPT; c4 += 4) {
                float4 w4 = *reinterpret_cast<const float4*>(&wt[k * M + cc * CPT + c4]);
                wv[c4 + 0] = w4.x; wv[c4 + 1] = w4.y; wv[c4 + 2] = w4.z; wv[c4 + 3] = w4.w;
            }
            #pragma unroll
            for (int r = 0; r < RPT; ++r)
                #pragma unroll
                for (int j = 0; j < CPT; ++j)
                    acc[r][j] = fmaf(xr[r], wv[j], acc[r][j]);
        }
        __syncthreads();
    }
    #pragma unroll
    for (int r = 0; r < RPT; ++r) {
        int row = row0 + rr * RPT + r;
        if (row < N) {
            #pragma unroll
            for (int c4 = 0; c4 < CPT; c4 += 4)
                *reinterpret_cast<float4*>(&O[(size_t)row * M + cc * CPT + c4]) =
                    make_float4(acc[r][c4], acc[r][c4 + 1], acc[r][c4 + 2], acc[r][c4 + 3]);
        }
    }
}

// ---------------- per-node/head attention logits ----------------

template <int H, int C>
__global__ __launch_bounds__(256) void alpha_k(const float* __restrict__ Hm, const float* __restrict__ a_s,
                                               const float* __restrict__ a_d,
                                               float* __restrict__ aS, float* __restrict__ aD, int N) {
    int t = blockIdx.x * blockDim.x + threadIdx.x;
    int n = t / H, hd = t - n * H;
    if (n >= N) return;
    const float4* hp = reinterpret_cast<const float4*>(Hm + (size_t)n * (H * C) + hd * C);
    const float4* as4 = reinterpret_cast<const float4*>(a_s + hd * C);
    const float4* ad4 = reinterpret_cast<const float4*>(a_d + hd * C);
    float ss = 0.f, sd = 0.f;
    #pragma unroll
    for (int c = 0; c < C / 4; ++c) {
        float4 v = hp[c];
        float4 s4 = as4[c];
        float4 d4 = ad4[c];
        ss += v.x * s4.x + v.y * s4.y + v.z * s4.z + v.w * s4.w;
        sd += v.x * d4.x + v.y * d4.y + v.z * d4.z + v.w * d4.w;
    }
    aS[(size_t)n * H + hd] = ss;
    aD[(size_t)n * H + hd] = sd;
}

// ---------------- segment-softmax aggregation, one wave per dst node ----------------
// Fast path (deg < 64): lane-per-edge logits, simple butterflies, normalized
// weights staged in LDS; payload loop has no exp and no aS gather.

template <int H, int C>
__global__ __launch_bounds__(256) void agg_k(const float* __restrict__ h, const float* __restrict__ aS,
                                             const float* __restrict__ aD, const int* __restrict__ off,
                                             const int* __restrict__ esrc, const float* __restrict__ bias,
                                             float* __restrict__ out, int N) {
    constexpr int M = H * C;
    constexpr int CPL = M / 64;  // 2 for M=128, 1 for M=64
    __shared__ float wlds[4][64][H];
    __shared__ int slds[4][64];
    const int wslot = threadIdx.x >> 6;
    int node = (blockIdx.x * blockDim.x + threadIdx.x) >> 6;
    if (node >= N) return;
    const int lane = threadIdx.x & 63;

    float adv[H], asv[H];
    if constexpr (H == 4) {
        float4 t = *reinterpret_cast<const float4*>(aD + (size_t)node * 4);
        adv[0] = t.x; adv[1] = t.y; adv[2] = t.z; adv[3] = t.w;
        float4 u = *reinterpret_cast<const float4*>(aS + (size_t)node * 4);
        asv[0] = u.x; asv[1] = u.y; asv[2] = u.z; asv[3] = u.w;
    } else {
        adv[0] = aD[node]; asv[0] = aS[node];
    }
    float eself[H];
    #pragma unroll
    for (int q = 0; q < H; ++q) eself[q] = leaky(asv[q] + adv[q]);

    const int s0 = off[node], s1 = off[node + 1];
    const int deg = s1 - s0;
    const int ch0 = lane * CPL;
    const int hd = ch0 / C;

    if (deg < 64) {
        // ---- weight phase: one lane per incident edge (self loop on lane==deg) ----
        float ev[H];
        int sv;
        if (lane < deg) {
            sv = esrc[s0 + lane];
            if constexpr (H == 4) {
                float4 u = *reinterpret_cast<const float4*>(aS + (size_t)sv * 4);
                ev[0] = leaky(u.x + adv[0]); ev[1] = leaky(u.y + adv[1]);
                ev[2] = leaky(u.z + adv[2]); ev[3] = leaky(u.w + adv[3]);
            } else {
                ev[0] = leaky(aS[sv] + adv[0]);
            }
        } else if (lane == deg) {
            sv = node;
            #pragma unroll
            for (int q = 0; q < H; ++q) ev[q] = eself[q];
        } else {
            sv = node;
            #pragma unroll
            for (int q = 0; q < H; ++q) ev[q] = NEG_BIG;
        }
        float m[H];
        #pragma unroll
        for (int q = 0; q < H; ++q) m[q] = ev[q];
        #pragma unroll
        for (int d = 1; d < 64; d <<= 1) {
            #pragma unroll
            for (int q = 0; q < H; ++q) m[q] = fmaxf(m[q], __shfl_xor(m[q], d));
        }
        float p[H], dsum[H];
        #pragma unroll
        for (int q = 0; q < H; ++q) {
            p[q] = (lane <= deg) ? __expf(ev[q] - m[q]) : 0.f;
            dsum[q] = p[q];
        }
        #pragma unroll
        for (int d = 1; d < 64; d <<= 1) {
            #pragma unroll
            for (int q = 0; q < H; ++q) dsum[q] += __shfl_xor(dsum[q], d);
        }
        #pragma unroll
        for (int q = 0; q < H; ++q) wlds[wslot][lane][q] = p[q] * (1.f / (dsum[q] + EPS_F));
        slds[wslot][lane] = sv;

        // ---- payload: no exp, no aS gather ----
        float acc0 = 0.f, acc1 = 0.f;
        const int cnt = deg + 1;
        int j = 0;
        for (; j + 8 <= cnt; j += 8) {
            int s8[8]; float w8[8];
            #pragma unroll
            for (int t = 0; t < 8; ++t) { s8[t] = slds[wslot][j + t]; w8[t] = wlds[wslot][j + t][hd]; }
            if constexpr (CPL == 2) {
                float2 hv[8];
                #pragma unroll
                for (int t = 0; t < 8; ++t) hv[t] = *reinterpret_cast<const float2*>(h + (size_t)s8[t] * M + ch0);
                #pragma unroll
                for (int t = 0; t < 8; ++t) { acc0 = fmaf(w8[t], hv[t].x, acc0); acc1 = fmaf(w8[t], hv[t].y, acc1); }
            } else {
                float hv[8];
                #pragma unroll
                for (int t = 0; t < 8; ++t) hv[t] = h[(size_t)s8[t] * M + ch0];
                #pragma unroll
                for (int t = 0; t < 8; ++t) acc0 = fmaf(w8[t], hv[t], acc0);
            }
        }
        for (; j < cnt; ++j) {
            int s = slds[wslot][j];
            float wq = wlds[wslot][j][hd];
            if constexpr (CPL == 2) {
                float2 hv = *reinterpret_cast<const float2*>(h + (size_t)s * M + ch0);
                acc0 = fmaf(wq, hv.x, acc0);
                acc1 = fmaf(wq, hv.y, acc1);
            } else {
                acc0 = fmaf(wq, h[(size_t)s * M + ch0], acc0);
            }
        }
        if constexpr (CPL == 2) {
            float2 o;
            o.x = acc0 + bias[ch0];
            o.y = acc1 + bias[ch0 + 1];
            *reinterpret_cast<float2*>(out + (size_t)node * M + ch0) = o;
        } else {
            out[(size_t)node * M + ch0] = acc0 + bias[ch0];
        }
    } else {
        // ---- fallback (deg >= 64): online softmax + butterfly merge ----
        float m[H], dsum[H];
        #pragma unroll
        for (int q = 0; q < H; ++q) { m[q] = eself[q]; dsum[q] = 0.f; }
        for (int i = s0 + lane; i < s1; i += 64) {
            int s = esrc[i];
            if constexpr (H == 4) {
                float4 u = *reinterpret_cast<const float4*>(aS + (size_t)s * 4);
                float evv[4] = {u.x, u.y, u.z, u.w};
                #pragma unroll
                for (int q = 0; q < 4; ++q) {
                    float e = leaky(evv[q] + adv[q]);
                    float nm = fmaxf(m[q], e);
                    dsum[q] = dsum[q] * __expf(m[q] - nm) + __expf(e - nm);
                    m[q] = nm;
                }
            } else {
                float e = leaky(aS[s] + adv[0]);
                float nm = fmaxf(m[0], e);
                dsum[0] = dsum[0] * __expf(m[0] - nm) + __expf(e - nm);
                m[0] = nm;
            }
        }
        #pragma unroll
        for (int q = 0; q < H; ++q) {
            #pragma unroll
            for (int d = 1; d < 64; d <<= 1) {
                float om = __shfl_xor(m[q], d);
                float od = __shfl_xor(dsum[q], d);
                float nm = fmaxf(m[q], om);
                dsum[q] = dsum[q] * __expf(m[q] - nm) + od * __expf(om - nm);
                m[q] = nm;
            }
            dsum[q] += __expf(eself[q] - m[q]);
        }
        const float advh = adv[hd];
        const float Mh = m[hd];
        float acc0 = 0.f, acc1 = 0.f;
        int i = s0;
        for (; i + 8 <= s1; i += 8) {
            int sv8[8]; float lv[8];
            #pragma unroll
            for (int t = 0; t < 8; ++t) sv8[t] = esrc[i + t];
            #pragma unroll
            for (int t = 0; t < 8; ++t) lv[t] = aS[(size_t)sv8[t] * H + hd];
            if constexpr (CPL == 2) {
                float2 hv[8];
                #pragma unroll
                for (int t = 0; t < 8; ++t) hv[t] = *reinterpret_cast<const float2*>(h + (size_t)sv8[t] * M + ch0);
                #pragma unroll
                for (int t = 0; t < 8; ++t) {
                    float wq = __expf(leaky(lv[t] + advh) - Mh);
                    acc0 = fmaf(wq, hv[t].x, acc0);
                    acc1 = fmaf(wq, hv[t].y, acc1);
                }
            } else {
                float hv[8];
                #pragma unroll
                for (int t = 0; t < 8; ++t) hv[t] = h[(size_t)sv8[t] * M + ch0];
                #pragma unroll
                for (int t = 0; t < 8; ++t) {
                    float wq = __expf(leaky(lv[t] + advh) - Mh);
                    acc0 = fmaf(wq, hv[t], acc0);
                }
            }
        }
        for (; i < s1; ++i) {
            int s = esrc[i];
            float wq = __expf(leaky(aS[(size_t)s * H + hd] + advh) - Mh);
            if constexpr (CPL == 2) {
                float2 hv = *reinterpret_cast<const float2*>(h + (size_t)s * M + ch0);
                acc0 = fmaf(wq, hv.x, acc0);
                acc1 = fmaf(wq, hv.y, acc1);
            } else {
                acc0 = fmaf(wq, h[(size_t)s * M + ch0], acc0);
            }
        }
        {
            float ws = __expf(eself[hd] - Mh);
            if constexpr (CPL == 2) {
                float2 hv = *reinterpret_cast<const float2*>(h + (size_t)node * M + ch0);
                acc0 = fmaf(ws, hv.x, acc0);
                acc1 = fmaf(ws, hv.y, acc1);
            } else {
                acc0 = fmaf(ws, h[(size_t)node * M + ch0], acc0);
            }
        }
        float inv = 1.f / (dsum[hd] + EPS_F);
        if constexpr (CPL == 2) {
            float2 o;
            o.x = acc0 * inv + bias[ch0];
            o.y = acc1 * inv + bias[ch0 + 1];
            *reinterpret_cast<float2*>(out + (size_t)node * M + ch0) = o;
        } else {
            out[(size_t)node * M + ch0] = acc0 * inv + bias[ch0];
        }
    }
}

// ---------------- launch ----------------

extern "C" void kernel_launch(void* const* d_in, const int* in_sizes, int n_in,
                              void* d_out, int out_size, void* d_ws, size_t ws_size,
                              hipStream_t stream) {
    const float* x   = (const float*)d_in[0];
    const int*   ei  = (const int*)d_in[1];
    const float* W0  = (const float*)d_in[2];
    const float* as0 = (const float*)d_in[3];
    const float* ad0 = (const float*)d_in[4];
    const float* b0  = (const float*)d_in[5];
    const float* W1  = (const float*)d_in[6];
    const float* as1 = (const float*)d_in[7];
    const float* ad1 = (const float*)d_in[8];
    const float* b1  = (const float*)d_in[9];
    const float* W2  = (const float*)d_in[10];
    const float* as2 = (const float*)d_in[11];
    const float* ad2 = (const float*)d_in[12];
    const float* b2  = (const float*)d_in[13];

    const int N = in_sizes[0] / 128;  // 50000
    const int E = in_sizes[1] / 2;    // 800000
    const int* esrc_in = ei;
    const int* edst_in = ei + E;

    char* w = (char*)d_ws;
    auto carve = [&](size_t bytes) -> char* {
        char* p = w;
        w += (bytes + 255) & ~(size_t)255;
        return p;
    };
    int*   off  = (int*)carve((size_t)(N + 1) * 4);
    int*   cnt  = (int*)carve((size_t)N * 4);
    int*   es   = (int*)carve((size_t)E * 4);
    float* aS   = (float*)carve((size_t)N * 4 * sizeof(float));
    float* aD   = (float*)carve((size_t)N * 4 * sizeof(float));
    float* bufH = (float*)carve((size_t)N * 128 * sizeof(float));
    float* bufO = (float*)carve((size_t)N * 128 * sizeof(float));
    (void)ws_size; (void)n_in; (void)out_size;

    // CSR by dst (self-loops handled implicitly in agg_k)
    hipMemsetAsync(cnt, 0, (size_t)N * 4, stream);
    hist_k<<<(E + 255) / 256, 256, 0, stream>>>(edst_in, cnt, E);
    scan_k<<<1, 1024, 0, stream>>>(cnt, off, N);
    hipMemsetAsync(cnt, 0, (size_t)N * 4, stream);
    scat_k<<<(E + 255) / 256, 256, 0, stream>>>(esrc_in, edst_in, off, cnt, es, E);

    const int GEMM_GRID = (N + 127) / 128;
    const int AGG_GRID = (N + 3) / 4;

    // layer 0: 128 -> 4x32
    gemm_k<128><<<GEMM_GRID, 256, 0, stream>>>(x, W0, bufH, N);
    alpha_k<4, 32><<<((N * 4) + 255) / 256, 256, 0, stream>>>(bufH, as0, ad0, aS, aD, N);
    agg_k<4, 32><<<AGG_GRID, 256, 0, stream>>>(bufH, aS, aD, off, es, b0, bufO, N);

    // layer 1: 128 -> 4x32
    gemm_k<128><<<GEMM_GRID, 256, 0, stream>>>(bufO, W1, bufH, N);
    alpha_k<4, 32><<<((N * 4) + 255) / 256, 256, 0, stream>>>(bufH, as1, ad1, aS, aD, N);
    agg_k<4, 32><<<AGG_GRID, 256, 0, stream>>>(bufH, aS, aD, off, es, b1, bufO, N);

    // layer 2: 128 -> 1x64
    gemm_k<64><<<GEMM_GRID, 256, 0, stream>>>(bufO, W2, bufH, N);
    alpha_k<1, 64><<<(N + 255) / 256, 256, 0, stream>>>(bufH, as2, ad2, aS, aD, N);
    agg_k<1, 64><<<AGG_GRID, 256, 0, stream>>>(bufH, aS, aD, off, es, b2, (float*)d_out, N);
}

// Round 4
// 384.180 us; speedup vs baseline: 1.5381x; 1.1101x over previous
//
#include <hip/hip_runtime.h>
#include <cstdint>
#include <cstddef>

#define NEG_SLOPE 0.2f
#define EPS_F 1e-16f

static __device__ __forceinline__ float leaky(float x) { return x > 0.f ? x : NEG_SLOPE * x; }

// ---------------- CSR build ----------------

__global__ __launch_bounds__(256) void hist_k(const int* __restrict__ dst, int* __restrict__ cnt, int E) {
    int i = blockIdx.x * blockDim.x + threadIdx.x;
    if (i < E) atomicAdd(&cnt[dst[i]], 1);
}

__global__ __launch_bounds__(1024) void scan_k(const int* __restrict__ cnt, int* __restrict__ off, int N) {
    __shared__ int wsum[16];
    int tid = threadIdx.x;
    int lane = tid & 63, wid = tid >> 6;
    int running = 0;
    for (int base = 0; base < N; base += 1024) {
        int i = base + tid;
        int v = (i < N) ? cnt[i] : 0;
        int iv = v;
        #pragma unroll
        for (int d = 1; d < 64; d <<= 1) {
            int t = __shfl_up(iv, d);
            if (lane >= d) iv += t;
        }
        if (lane == 63) wsum[wid] = iv;
        __syncthreads();
        if (tid < 16) {
            int s = wsum[tid];
            #pragma unroll
            for (int d = 1; d < 16; d <<= 1) {
                int t = __shfl_up(s, d);
                if (tid >= d) s += t;
            }
            wsum[tid] = s;
        }
        __syncthreads();
        int add = wid ? wsum[wid - 1] : 0;
        if (i < N) off[i + 1] = running + add + iv;
        int ct = wsum[15];
        __syncthreads();
        running += ct;
    }
    if (tid == 0) off[0] = 0;
}

__global__ __launch_bounds__(256) void scat_k(const int* __restrict__ src, const int* __restrict__ dst,
                                              const int* __restrict__ off, int* __restrict__ cnt,
                                              int* __restrict__ esrc, int E) {
    int i = blockIdx.x * blockDim.x + threadIdx.x;
    if (i < E) {
        int d = dst[i];
        int p = off[d] + atomicAdd(&cnt[d], 1);
        esrc[p] = src[i];
    }
}

// ---------------- GEMM with fused alpha epilogue ----------------
// [N,128] @ [128,M] -> [N,M]; also aS[n,h] = <O_row_head, a_s>, aD likewise.

template <int M, int H>
__global__ __launch_bounds__(256, 2) void gemm_k(const float* __restrict__ X, const float* __restrict__ W,
                                                 const float* __restrict__ a_s, const float* __restrict__ a_d,
                                                 float* __restrict__ O, float* __restrict__ aS,
                                                 float* __restrict__ aD, int N) {
    constexpr int K = 128, BK = 16, ROWS = 128;
    constexpr int CPT = 8;
    constexpr int CT = M / CPT;
    constexpr int RT = 256 / CT;
    constexpr int RPT = ROWS / RT;
    constexpr int XP = ROWS + 4;
    constexpr int C = M / H;
    constexpr int REDW = C / CPT;  // threads per (row, head): 4 (M=128) or 8 (M=64)
    __shared__ float xsT[BK * XP];
    __shared__ float wt[BK * M];

    const int tid = threadIdx.x;
    const int cc = tid % CT;
    const int rr = tid / CT;
    const int row0 = blockIdx.x * ROWS;

    float acc[RPT][CPT];
    #pragma unroll
    for (int r = 0; r < RPT; ++r)
        #pragma unroll
        for (int j = 0; j < CPT; ++j) acc[r][j] = 0.f;

    for (int k0 = 0; k0 < K; k0 += BK) {
        #pragma unroll
        for (int t = tid; t < ROWS * (BK / 4); t += 256) {
            int r = t >> 2;
            int kk = t & 3;
            int row = row0 + r;
            float4 v = make_float4(0.f, 0.f, 0.f, 0.f);
            if (row < N) v = *reinterpret_cast<const float4*>(&X[(size_t)row * K + k0 + kk * 4]);
            xsT[(kk * 4 + 0) * XP + r] = v.x;
            xsT[(kk * 4 + 1) * XP + r] = v.y;
            xsT[(kk * 4 + 2) * XP + r] = v.z;
            xsT[(kk * 4 + 3) * XP + r] = v.w;
        }
        #pragma unroll
        for (int t = tid; t < BK * (M / 4); t += 256) {
            int c4 = t % (M / 4);
            int k = t / (M / 4);
            *reinterpret_cast<float4*>(&wt[k * M + c4 * 4]) =
                *reinterpret_cast<const float4*>(&W[(size_t)(k0 + k) * M + c4 * 4]);
        }
        __syncthreads();
        #pragma unroll
        for (int k = 0; k < BK; ++k) {
            float xr[RPT];
            #pragma unroll
            for (int r4 = 0; r4 < RPT; r4 += 4) {
                float4 xv = *reinterpret_cast<const float4*>(&xsT[k * XP + rr * RPT + r4]);
                xr[r4 + 0] = xv.x; xr[r4 + 1] = xv.y; xr[r4 + 2] = xv.z; xr[r4 + 3] = xv.w;
            }
            float wv[CPT];
            #pragma unroll
            for (int c4 = 0; c4 < CPT; c4 += 4) {
                float4 w4 = *reinterpret_cast<const float4*>(&wt[k * M + cc * CPT + c4]);
                wv[c4 + 0] = w4.x; wv[c4 + 1] = w4.y; wv[c4 + 2] = w4.z; wv[c4 + 3] = w4.w;
            }
            #pragma unroll
            for (int r = 0; r < RPT; ++r)
                #pragma unroll
                for (int j = 0; j < CPT; ++j)
                    acc[r][j] = fmaf(xr[r], wv[j], acc[r][j]);
        }
        __syncthreads();
    }

    // alpha coefficients for this thread's 8 columns (flat [H][C] layout == flat col index)
    float asr[CPT], adr[CPT];
    #pragma unroll
    for (int c4 = 0; c4 < CPT; c4 += 4) {
        float4 t1 = *reinterpret_cast<const float4*>(a_s + cc * CPT + c4);
        asr[c4 + 0] = t1.x; asr[c4 + 1] = t1.y; asr[c4 + 2] = t1.z; asr[c4 + 3] = t1.w;
        float4 t2 = *reinterpret_cast<const float4*>(a_d + cc * CPT + c4);
        adr[c4 + 0] = t2.x; adr[c4 + 1] = t2.y; adr[c4 + 2] = t2.z; adr[c4 + 3] = t2.w;
    }
    const int head = (cc * CPT) / C;

    #pragma unroll
    for (int r = 0; r < RPT; ++r) {
        int row = row0 + rr * RPT + r;
        float ps = 0.f, pd = 0.f;
        #pragma unroll
        for (int j = 0; j < CPT; ++j) {
            ps = fmaf(acc[r][j], asr[j], ps);
            pd = fmaf(acc[r][j], adr[j], pd);
        }
        #pragma unroll
        for (int d = 1; d < REDW; d <<= 1) {
            ps += __shfl_xor(ps, d);
            pd += __shfl_xor(pd, d);
        }
        if (row < N) {
            #pragma unroll
            for (int c4 = 0; c4 < CPT; c4 += 4)
                *reinterpret_cast<float4*>(&O[(size_t)row * M + cc * CPT + c4]) =
                    make_float4(acc[r][c4], acc[r][c4 + 1], acc[r][c4 + 2], acc[r][c4 + 3]);
            if ((cc & (REDW - 1)) == 0) {
                aS[(size_t)row * H + head] = ps;
                aD[(size_t)row * H + head] = pd;
            }
        }
    }
}

// ---------------- segment-softmax aggregation, one wave per dst node ----------------
// Fast path (deg < 64): unnormalized exp weights (no max-sub — logits are O(10),
// exp range safe), no cross-lane reductions; denominator accumulated for free in
// the payload loop; batch-0 h rows prefetched before the weight phase.

template <int H, int C>
__global__ __launch_bounds__(256) void agg_k(const float* __restrict__ h, const float* __restrict__ aS,
                                             const float* __restrict__ aD, const int* __restrict__ off,
                                             const int* __restrict__ esrc, const float* __restrict__ bias,
                                             float* __restrict__ out, int N) {
    constexpr int M = H * C;
    constexpr int CPL = M / 64;  // 2 for M=128, 1 for M=64
    __shared__ float wlds[4][64][H];
    const int wslot = threadIdx.x >> 6;
    int node = (blockIdx.x * blockDim.x + threadIdx.x) >> 6;
    if (node >= N) return;
    const int lane = threadIdx.x & 63;

    float adv[H], asv[H];
    if constexpr (H == 4) {
        float4 t = *reinterpret_cast<const float4*>(aD + (size_t)node * 4);
        adv[0] = t.x; adv[1] = t.y; adv[2] = t.z; adv[3] = t.w;
        float4 u = *reinterpret_cast<const float4*>(aS + (size_t)node * 4);
        asv[0] = u.x; asv[1] = u.y; asv[2] = u.z; asv[3] = u.w;
    } else {
        adv[0] = aD[node]; asv[0] = aS[node];
    }
    float eself[H];
    #pragma unroll
    for (int q = 0; q < H; ++q) eself[q] = leaky(asv[q] + adv[q]);

    const int s0 = off[node], s1 = off[node + 1];
    const int deg = s1 - s0;
    const int ch0 = lane * CPL;
    const int hd = ch0 / C;

    if (deg < 64) {
        const int cnt = deg + 1;
        float2 hv2[16];
        float hv1[16];
        int sB[16];
        // ---- batch-0 prefetch: src ids read uniformly, h rows issued early ----
        #pragma unroll
        for (int t = 0; t < 16; ++t) {
            int idx = s0 + t;
            sB[t] = (idx < s1) ? esrc[idx] : node;
        }
        if constexpr (CPL == 2) {
            #pragma unroll
            for (int t = 0; t < 16; ++t)
                hv2[t] = *reinterpret_cast<const float2*>(h + (size_t)sB[t] * M + ch0);
        } else {
            #pragma unroll
            for (int t = 0; t < 16; ++t) hv1[t] = h[(size_t)sB[t] * M + ch0];
        }
        // ---- weight phase: one lane per edge, unnormalized exp, no reductions ----
        {
            int svi = s0 + lane;
            int sv = (svi < s1) ? esrc[svi] : node;
            if constexpr (H == 4) {
                float4 u = *reinterpret_cast<const float4*>(aS + (size_t)sv * 4);
                float w0, w1, w2, w3;
                if (lane < deg) {
                    w0 = __expf(leaky(u.x + adv[0]));
                    w1 = __expf(leaky(u.y + adv[1]));
                    w2 = __expf(leaky(u.z + adv[2]));
                    w3 = __expf(leaky(u.w + adv[3]));
                } else if (lane == deg) {
                    w0 = __expf(eself[0]); w1 = __expf(eself[1]);
                    w2 = __expf(eself[2]); w3 = __expf(eself[3]);
                } else {
                    w0 = w1 = w2 = w3 = 0.f;
                }
                *reinterpret_cast<float4*>(&wlds[wslot][lane][0]) = make_float4(w0, w1, w2, w3);
            } else {
                float u = aS[sv];
                float w0 = (lane < deg) ? __expf(leaky(u + adv[0]))
                         : (lane == deg) ? __expf(eself[0]) : 0.f;
                wlds[wslot][lane][0] = w0;
            }
        }
        asm volatile("s_waitcnt lgkmcnt(0)" ::: "memory");

        float acc0 = 0.f, acc1 = 0.f, wsum = 0.f;
        // consume batch 0
        #pragma unroll
        for (int t = 0; t < 16; ++t) {
            float wq = wlds[wslot][t][hd];
            wsum += wq;
            if constexpr (CPL == 2) {
                acc0 = fmaf(wq, hv2[t].x, acc0);
                acc1 = fmaf(wq, hv2[t].y, acc1);
            } else {
                acc0 = fmaf(wq, hv1[t], acc0);
            }
        }
        // batches >= 1 (zero weights make over-run harmless)
        for (int j = 16; j < cnt; j += 16) {
            #pragma unroll
            for (int t = 0; t < 16; ++t) {
                int idx = s0 + j + t;
                sB[t] = (idx < s1) ? esrc[idx] : node;
            }
            if constexpr (CPL == 2) {
                #pragma unroll
                for (int t = 0; t < 16; ++t)
                    hv2[t] = *reinterpret_cast<const float2*>(h + (size_t)sB[t] * M + ch0);
            } else {
                #pragma unroll
                for (int t = 0; t < 16; ++t) hv1[t] = h[(size_t)sB[t] * M + ch0];
            }
            #pragma unroll
            for (int t = 0; t < 16; ++t) {
                float wq = wlds[wslot][j + t][hd];
                wsum += wq;
                if constexpr (CPL == 2) {
                    acc0 = fmaf(wq, hv2[t].x, acc0);
                    acc1 = fmaf(wq, hv2[t].y, acc1);
                } else {
                    acc0 = fmaf(wq, hv1[t], acc0);
                }
            }
        }
        float inv = 1.f / (wsum + EPS_F);
        if constexpr (CPL == 2) {
            float2 o;
            o.x = acc0 * inv + bias[ch0];
            o.y = acc1 * inv + bias[ch0 + 1];
            *reinterpret_cast<float2*>(out + (size_t)node * M + ch0) = o;
        } else {
            out[(size_t)node * M + ch0] = acc0 * inv + bias[ch0];
        }
    } else {
        // ---- fallback (deg >= 64): online softmax + butterfly merge ----
        float m[H], dsum[H];
        #pragma unroll
        for (int q = 0; q < H; ++q) { m[q] = eself[q]; dsum[q] = 0.f; }
        for (int i = s0 + lane; i < s1; i += 64) {
            int s = esrc[i];
            if constexpr (H == 4) {
                float4 u = *reinterpret_cast<const float4*>(aS + (size_t)s * 4);
                float evv[4] = {u.x, u.y, u.z, u.w};
                #pragma unroll
                for (int q = 0; q < 4; ++q) {
                    float e = leaky(evv[q] + adv[q]);
                    float nm = fmaxf(m[q], e);
                    dsum[q] = dsum[q] * __expf(m[q] - nm) + __expf(e - nm);
                    m[q] = nm;
                }
            } else {
                float e = leaky(aS[s] + adv[0]);
                float nm = fmaxf(m[0], e);
                dsum[0] = dsum[0] * __expf(m[0] - nm) + __expf(e - nm);
                m[0] = nm;
            }
        }
        #pragma unroll
        for (int q = 0; q < H; ++q) {
            #pragma unroll
            for (int d = 1; d < 64; d <<= 1) {
                float om = __shfl_xor(m[q], d);
                float od = __shfl_xor(dsum[q], d);
                float nm = fmaxf(m[q], om);
                dsum[q] = dsum[q] * __expf(m[q] - nm) + od * __expf(om - nm);
                m[q] = nm;
            }
            dsum[q] += __expf(eself[q] - m[q]);
        }
        const float advh = adv[hd];
        const float Mh = m[hd];
        float acc0 = 0.f, acc1 = 0.f;
        int i = s0;
        for (; i + 8 <= s1; i += 8) {
            int sv8[8]; float lv[8];
            #pragma unroll
            for (int t = 0; t < 8; ++t) sv8[t] = esrc[i + t];
            #pragma unroll
            for (int t = 0; t < 8; ++t) lv[t] = aS[(size_t)sv8[t] * H + hd];
            if constexpr (CPL == 2) {
                float2 hv[8];
                #pragma unroll
                for (int t = 0; t < 8; ++t) hv[t] = *reinterpret_cast<const float2*>(h + (size_t)sv8[t] * M + ch0);
                #pragma unroll
                for (int t = 0; t < 8; ++t) {
                    float wq = __expf(leaky(lv[t] + advh) - Mh);
                    acc0 = fmaf(wq, hv[t].x, acc0);
                    acc1 = fmaf(wq, hv[t].y, acc1);
                }
            } else {
                float hv[8];
                #pragma unroll
                for (int t = 0; t < 8; ++t) hv[t] = h[(size_t)sv8[t] * M + ch0];
                #pragma unroll
                for (int t = 0; t < 8; ++t) {
                    float wq = __expf(leaky(lv[t] + advh) - Mh);
                    acc0 = fmaf(wq, hv[t], acc0);
                }
            }
        }
        for (; i < s1; ++i) {
            int s = esrc[i];
            float wq = __expf(leaky(aS[(size_t)s * H + hd] + advh) - Mh);
            if constexpr (CPL == 2) {
                float2 hv = *reinterpret_cast<const float2*>(h + (size_t)s * M + ch0);
                acc0 = fmaf(wq, hv.x, acc0);
                acc1 = fmaf(wq, hv.y, acc1);
            } else {
                acc0 = fmaf(wq, h[(size_t)s * M + ch0], acc0);
            }
        }
        {
            float ws = __expf(eself[hd] - Mh);
            if constexpr (CPL == 2) {
                float2 hv = *reinterpret_cast<const float2*>(h + (size_t)node * M + ch0);
                acc0 = fmaf(ws, hv.x, acc0);
                acc1 = fmaf(ws, hv.y, acc1);
            } else {
                acc0 = fmaf(ws, h[(size_t)node * M + ch0], acc0);
            }
        }
        float inv = 1.f / (dsum[hd] + EPS_F);
        if constexpr (CPL == 2) {
            float2 o;
            o.x = acc0 * inv + bias[ch0];
            o.y = acc1 * inv + bias[ch0 + 1];
            *reinterpret_cast<float2*>(out + (size_t)node * M + ch0) = o;
        } else {
            out[(size_t)node * M + ch0] = acc0 * inv + bias[ch0];
        }
    }
}

// ---------------- launch ----------------

extern "C" void kernel_launch(void* const* d_in, const int* in_sizes, int n_in,
                              void* d_out, int out_size, void* d_ws, size_t ws_size,
                              hipStream_t stream) {
    const float* x   = (const float*)d_in[0];
    const int*   ei  = (const int*)d_in[1];
    const float* W0  = (const float*)d_in[2];
    const float* as0 = (const float*)d_in[3];
    const float* ad0 = (const float*)d_in[4];
    const float* b0  = (const float*)d_in[5];
    const float* W1  = (const float*)d_in[6];
    const float* as1 = (const float*)d_in[7];
    const float* ad1 = (const float*)d_in[8];
    const float* b1  = (const float*)d_in[9];
    const float* W2  = (const float*)d_in[10];
    const float* as2 = (const float*)d_in[11];
    const float* ad2 = (const float*)d_in[12];
    const float* b2  = (const float*)d_in[13];

    const int N = in_sizes[0] / 128;  // 50000
    const int E = in_sizes[1] / 2;    // 800000
    const int* esrc_in = ei;
    const int* edst_in = ei + E;

    char* w = (char*)d_ws;
    auto carve = [&](size_t bytes) -> char* {
        char* p = w;
        w += (bytes + 255) & ~(size_t)255;
        return p;
    };
    int*   off  = (int*)carve((size_t)(N + 1) * 4);
    int*   cnt  = (int*)carve((size_t)N * 4);
    int*   es   = (int*)carve((size_t)E * 4);
    float* aS   = (float*)carve((size_t)N * 4 * sizeof(float));
    float* aD   = (float*)carve((size_t)N * 4 * sizeof(float));
    float* bufH = (float*)carve((size_t)N * 128 * sizeof(float));
    float* bufO = (float*)carve((size_t)N * 128 * sizeof(float));
    (void)ws_size; (void)n_in; (void)out_size;

    // CSR by dst (self-loops handled implicitly in agg_k)
    hipMemsetAsync(cnt, 0, (size_t)N * 4, stream);
    hist_k<<<(E + 255) / 256, 256, 0, stream>>>(edst_in, cnt, E);
    scan_k<<<1, 1024, 0, stream>>>(cnt, off, N);
    hipMemsetAsync(cnt, 0, (size_t)N * 4, stream);
    scat_k<<<(E + 255) / 256, 256, 0, stream>>>(esrc_in, edst_in, off, cnt, es, E);

    const int GEMM_GRID = (N + 127) / 128;
    const int AGG_GRID = (N + 3) / 4;

    // layer 0: 128 -> 4x32
    gemm_k<128, 4><<<GEMM_GRID, 256, 0, stream>>>(x, W0, as0, ad0, bufH, aS, aD, N);
    agg_k<4, 32><<<AGG_GRID, 256, 0, stream>>>(bufH, aS, aD, off, es, b0, bufO, N);

    // layer 1: 128 -> 4x32
    gemm_k<128, 4><<<GEMM_GRID, 256, 0, stream>>>(bufO, W1, as1, ad1, bufH, aS, aD, N);
    agg_k<4, 32><<<AGG_GRID, 256, 0, stream>>>(bufH, aS, aD, off, es, b1, bufO, N);

    // layer 2: 128 -> 1x64
    gemm_k<64, 1><<<GEMM_GRID, 256, 0, stream>>>(bufO, W2, as2, ad2, bufH, aS, aD, N);
    agg_k<1, 64><<<AGG_GRID, 256, 0, stream>>>(bufH, aS, aD, off, es, b2, (float*)d_out, N);
}